// Round 1
// baseline (279.195 us; speedup 1.0000x reference)
//
#include <hip/hip_runtime.h>

// OctVolSynth: element-wise over 256^3 volume.
//   scaling = lut[label]; v = scaling*texture; v = (v==0) ? 1 : v;
//   out0 = parenchyma * v;  out1 = (label != 0) ? 1.0f : 0.0f
// Outputs concatenated flat: [final_volume (N), vessel_mask (N)] as float32.
//
// Memory-bound: 12 B/elem read + 8 B/elem write = 336 MB total -> ~55 us at
// 6.3 TB/s achievable HBM BW. LUT (302 floats) staged in LDS to avoid
// per-lane divergent global gather.

#define N_ELEMS (256 * 256 * 256)
#define LUT_SIZE 302
#define BLOCK 256
#define VEC 4

__global__ __launch_bounds__(BLOCK) void octvolsynth_kernel(
    const int* __restrict__ labels,
    const float* __restrict__ parenchyma,
    const float* __restrict__ texture,
    const float* __restrict__ lut,
    float* __restrict__ out)
{
    __shared__ float s_lut[LUT_SIZE];
    const int t = threadIdx.x;
    // cooperative LUT stage (302 > 256, so loop)
    for (int i = t; i < LUT_SIZE; i += BLOCK) s_lut[i] = lut[i];
    __syncthreads();

    const int vidx = blockIdx.x * BLOCK + t;   // index in units of 4 elements

    const int4   l4 = ((const int4*)labels)[vidx];
    const float4 p4 = ((const float4*)parenchyma)[vidx];
    const float4 x4 = ((const float4*)texture)[vidx];

    float4 fv, mv;

    {
        float v = s_lut[l4.x] * x4.x;
        fv.x = p4.x * ((v == 0.0f) ? 1.0f : v);
        mv.x = (l4.x != 0) ? 1.0f : 0.0f;
    }
    {
        float v = s_lut[l4.y] * x4.y;
        fv.y = p4.y * ((v == 0.0f) ? 1.0f : v);
        mv.y = (l4.y != 0) ? 1.0f : 0.0f;
    }
    {
        float v = s_lut[l4.z] * x4.z;
        fv.z = p4.z * ((v == 0.0f) ? 1.0f : v);
        mv.z = (l4.z != 0) ? 1.0f : 0.0f;
    }
    {
        float v = s_lut[l4.w] * x4.w;
        fv.w = p4.w * ((v == 0.0f) ? 1.0f : v);
        mv.w = (l4.w != 0) ? 1.0f : 0.0f;
    }

    ((float4*)out)[vidx] = fv;
    ((float4*)(out + N_ELEMS))[vidx] = mv;
}

extern "C" void kernel_launch(void* const* d_in, const int* in_sizes, int n_in,
                              void* d_out, int out_size, void* d_ws, size_t ws_size,
                              hipStream_t stream) {
    const int*   labels     = (const int*)d_in[0];
    const float* parenchyma = (const float*)d_in[1];
    const float* texture    = (const float*)d_in[2];
    const float* lut        = (const float*)d_in[3];
    float* out = (float*)d_out;

    const int n_vec = N_ELEMS / VEC;          // 4,194,304 threads
    const int grid  = n_vec / BLOCK;          // 16,384 blocks, no tail
    octvolsynth_kernel<<<grid, BLOCK, 0, stream>>>(labels, parenchyma, texture, lut, out);
}